// Round 3
// baseline (539.817 us; speedup 1.0000x reference)
//
#include <hip/hip_runtime.h>
#include <hip/hip_bf16.h>

#define NN 8192
#define FIN 256
#define FO 128
#define JC 1024                 // per-wave k-chunk (8 waves cover 8192)
#define L2E 1.4426950408889634f
#define C2  0.28853900817779268f   // 0.2 * log2(e)

typedef __bf16 bf16x8 __attribute__((ext_vector_type(8)));
typedef __bf16 bf16x2 __attribute__((ext_vector_type(2)));
typedef float  f32x4  __attribute__((ext_vector_type(4)));

// ---------------------------------------------------------------------------
// Kernel 1: h = x@W (fp32 accum), write Bpack (bf16 MFMA-B-fragment layout),
//           f_src = h@a_src, f_dst = h@a_dst (fp32).
// Bpack element (kg, nt, lane=q*16+m, t) = h[j = kg*32+q*8+t][n = nt*16+m]
// ---------------------------------------------------------------------------
__global__ __launch_bounds__(256) void k_proj(
    const float* __restrict__ x, const float* __restrict__ W,
    const float* __restrict__ a_src, const float* __restrict__ a_dst,
    __bf16* __restrict__ Bp, float* __restrict__ f_src, float* __restrict__ f_dst)
{
  __shared__ float xs[16 * FIN];     // 16 KB x-tile
  __shared__ float fs[16], fd[16];
  const int tid = threadIdx.x;
  const int i0 = blockIdx.x * 16;

  const float4* xg = (const float4*)(x + (size_t)i0 * FIN);
  float4* xs4 = (float4*)xs;
  #pragma unroll
  for (int t = 0; t < 4; t++) xs4[tid + 256 * t] = xg[tid + 256 * t];
  if (tid < 16) { fs[tid] = 0.f; fd[tid] = 0.f; }
  __syncthreads();

  const int cq = tid & 31;    // column quad: cols c0..c0+3
  const int rg = tid >> 5;    // row group: rows r0, r0+1
  const int c0 = cq * 4;
  const int r0 = rg * 2;
  float acc0[4] = {0.f,0.f,0.f,0.f};
  float acc1[4] = {0.f,0.f,0.f,0.f};
  const float* xr0 = xs + r0 * FIN;
  const float* xr1 = xs + (r0 + 1) * FIN;

  for (int k = 0; k < FIN; k += 4) {
    float4 xa = *(const float4*)(xr0 + k);
    float4 xb = *(const float4*)(xr1 + k);
    #pragma unroll
    for (int kk = 0; kk < 4; kk++) {
      float4 wv = *(const float4*)(W + (size_t)(k + kk) * FO + c0);
      float xav = ((const float*)&xa)[kk];
      float xbv = ((const float*)&xb)[kk];
      acc0[0] += xav * wv.x; acc0[1] += xav * wv.y;
      acc0[2] += xav * wv.z; acc0[3] += xav * wv.w;
      acc1[0] += xbv * wv.x; acc1[1] += xbv * wv.y;
      acc1[2] += xbv * wv.z; acc1[3] += xbv * wv.w;
    }
  }

  float4 as = *(const float4*)(a_src + c0);
  float4 ad = *(const float4*)(a_dst + c0);
  float ps0 = acc0[0]*as.x + acc0[1]*as.y + acc0[2]*as.z + acc0[3]*as.w;
  float ps1 = acc1[0]*as.x + acc1[1]*as.y + acc1[2]*as.z + acc1[3]*as.w;
  float pd0 = acc0[0]*ad.x + acc0[1]*ad.y + acc0[2]*ad.z + acc0[3]*ad.w;
  float pd1 = acc1[0]*ad.x + acc1[1]*ad.y + acc1[2]*ad.z + acc1[3]*ad.w;
  atomicAdd(&fs[r0],     ps0);
  atomicAdd(&fs[r0 + 1], ps1);
  atomicAdd(&fd[r0],     pd0);
  atomicAdd(&fd[r0 + 1], pd1);

  const int j0 = i0 + r0;
  const int kg = j0 >> 5;
  const int q  = (j0 >> 3) & 3;
  const int t0 = j0 & 7;
  #pragma unroll
  for (int c = 0; c < 4; c++) {
    const int n = c0 + c;
    bf16x2 v;
    v[0] = (__bf16)acc0[c];
    v[1] = (__bf16)acc1[c];
    size_t idx = ((size_t)(kg * 8 + (n >> 4)) * 64 + q * 16 + (n & 15)) * 8 + t0;
    *(bf16x2*)(Bp + idx) = v;
  }
  __syncthreads();
  if (tid < 16) { f_src[i0 + tid] = fs[tid]; f_dst[i0 + tid] = fd[tid]; }
}

// ---------------------------------------------------------------------------
// Kernel 2: block owns 16 rows; 8 waves k-split 1024 cols each; LDS merge;
// fused softmax-divide; coalesced store. NO global atomics, no k_div.
// Depth-4 register prefetch pipeline on adj.
// ---------------------------------------------------------------------------
__global__ __launch_bounds__(512, 4) void k_attn(
    const float* __restrict__ adj, const __bf16* __restrict__ Bp,
    const float* __restrict__ f_src, const float* __restrict__ f_dst,
    float* __restrict__ out)
{
  __shared__ float fdls[NN];          // 32 KB: all f_dst
  __shared__ float accbuf[16 * FO];   // 8 KB
  __shared__ float lred[16];
  const int tid = threadIdx.x;
  const int i0 = blockIdx.x * 16;

  {
    const float4* src = (const float4*)f_dst;
    float4* dst = (float4*)fdls;
    #pragma unroll
    for (int t = 0; t < 4; t++) dst[tid + 512 * t] = src[tid + 512 * t];
  }
  ((float4*)accbuf)[tid] = (float4){0.f, 0.f, 0.f, 0.f};
  if (tid < 16) lred[tid] = 0.f;

  const int wv = tid >> 6;
  const int lane = tid & 63;
  const int m = lane & 15;
  const int q = lane >> 4;
  const float s  = f_src[i0 + m];
  const float s1 = s * L2E;
  const float s2 = s * 0.2f * L2E;
  __syncthreads();

  f32x4 acc[8];
  #pragma unroll
  for (int t = 0; t < 8; t++) acc[t] = (f32x4){0.f, 0.f, 0.f, 0.f};
  float psum = 0.f;

  const float*  adjp  = adj + (size_t)(i0 + m) * NN + wv * JC + q * 8;
  const __bf16* bb    = Bp + (size_t)wv * 32 * 4096 + lane * 8;
  const float*  dbase = fdls + wv * JC + q * 8;

  float4 pa0[4], pa1[4];
  #pragma unroll
  for (int p = 0; p < 4; p++) {
    pa0[p] = *(const float4*)(adjp + p * 32);
    pa1[p] = *(const float4*)(adjp + p * 32 + 4);
  }

#define ATTN_STEP(stc, u, PREFETCH)                                          \
  {                                                                          \
    float4 a0 = pa0[u], a1 = pa1[u];                                         \
    if (PREFETCH) {                                                          \
      pa0[u] = *(const float4*)(adjp + ((stc) + 4) * 32);                    \
      pa1[u] = *(const float4*)(adjp + ((stc) + 4) * 32 + 4);                \
    }                                                                        \
    const float4* dp = (const float4*)(dbase + (stc) * 32);                  \
    float4 d0 = dp[0], d1 = dp[1];                                           \
    float e0 = __builtin_amdgcn_exp2f(fmaxf(fmaf(d0.x, L2E, s1), fmaf(d0.x, C2, s2))); \
    float e1 = __builtin_amdgcn_exp2f(fmaxf(fmaf(d0.y, L2E, s1), fmaf(d0.y, C2, s2))); \
    float e2 = __builtin_amdgcn_exp2f(fmaxf(fmaf(d0.z, L2E, s1), fmaf(d0.z, C2, s2))); \
    float e3 = __builtin_amdgcn_exp2f(fmaxf(fmaf(d0.w, L2E, s1), fmaf(d0.w, C2, s2))); \
    float e4 = __builtin_amdgcn_exp2f(fmaxf(fmaf(d1.x, L2E, s1), fmaf(d1.x, C2, s2))); \
    float e5 = __builtin_amdgcn_exp2f(fmaxf(fmaf(d1.y, L2E, s1), fmaf(d1.y, C2, s2))); \
    float e6 = __builtin_amdgcn_exp2f(fmaxf(fmaf(d1.z, L2E, s1), fmaf(d1.z, C2, s2))); \
    float e7 = __builtin_amdgcn_exp2f(fmaxf(fmaf(d1.w, L2E, s1), fmaf(d1.w, C2, s2))); \
    float p0 = (a0.x > 0.f) ? e0 : 0.f;                                      \
    float p1 = (a0.y > 0.f) ? e1 : 0.f;                                      \
    float p2 = (a0.z > 0.f) ? e2 : 0.f;                                      \
    float p3 = (a0.w > 0.f) ? e3 : 0.f;                                      \
    float p4 = (a1.x > 0.f) ? e4 : 0.f;                                      \
    float p5 = (a1.y > 0.f) ? e5 : 0.f;                                      \
    float p6 = (a1.z > 0.f) ? e6 : 0.f;                                      \
    float p7 = (a1.w > 0.f) ? e7 : 0.f;                                      \
    psum += ((p0 + p1) + (p2 + p3)) + ((p4 + p5) + (p6 + p7));               \
    bf16x8 af;                                                               \
    af[0] = (__bf16)p0; af[1] = (__bf16)p1; af[2] = (__bf16)p2; af[3] = (__bf16)p3; \
    af[4] = (__bf16)p4; af[5] = (__bf16)p5; af[6] = (__bf16)p6; af[7] = (__bf16)p7; \
    const __bf16* bs = bb + (size_t)(stc) * 4096;                            \
    _Pragma("unroll")                                                        \
    for (int nt = 0; nt < 8; nt++) {                                         \
      bf16x8 bfrag = *(const bf16x8*)(bs + nt * 512);                        \
      acc[nt] = __builtin_amdgcn_mfma_f32_16x16x32_bf16(af, bfrag, acc[nt], 0, 0, 0); \
    }                                                                        \
  }

  for (int st = 0; st < 28; st += 4) {
    ATTN_STEP(st + 0, 0, true)
    ATTN_STEP(st + 1, 1, true)
    ATTN_STEP(st + 2, 2, true)
    ATTN_STEP(st + 3, 3, true)
  }
  ATTN_STEP(28, 0, false)
  ATTN_STEP(29, 1, false)
  ATTN_STEP(30, 2, false)
  ATTN_STEP(31, 3, false)
#undef ATTN_STEP

  // wave-level denominator: rows keyed by m live in lanes {m, m+16, m+32, m+48}
  psum += __shfl_xor(psum, 16);
  psum += __shfl_xor(psum, 32);
  if (lane < 16) atomicAdd(&lred[lane], psum);

  // merge numerator partials across waves in LDS (C/D: row=q*4+r, col=nt*16+m)
  #pragma unroll
  for (int nt = 0; nt < 8; nt++) {
    #pragma unroll
    for (int r = 0; r < 4; r++) {
      atomicAdd(&accbuf[(q * 4 + r) * FO + nt * 16 + m], acc[nt][r]);
    }
  }
  __syncthreads();

  // fused divide + coalesced store: 512 threads x float4 = 16 x 128
  const int row = tid >> 5;
  const float inv = 1.0f / lred[row];
  float4 v = ((const float4*)accbuf)[tid];
  float4 o;
  o.x = v.x * inv; o.y = v.y * inv; o.z = v.z * inv; o.w = v.w * inv;
  ((float4*)(out + (size_t)i0 * FO))[tid] = o;
}

extern "C" void kernel_launch(void* const* d_in, const int* in_sizes, int n_in,
                              void* d_out, int out_size, void* d_ws, size_t ws_size,
                              hipStream_t stream) {
  const float* x     = (const float*)d_in[0];
  const float* adj   = (const float*)d_in[1];
  const float* W     = (const float*)d_in[2];
  const float* a_src = (const float*)d_in[3];
  const float* a_dst = (const float*)d_in[4];
  float* out = (float*)d_out;

  char* ws = (char*)d_ws;
  __bf16* Bp   = (__bf16*)ws;                                  // 2 MB
  float* f_src = (float*)(ws + 2097152);                       // 32 KB
  float* f_dst = (float*)(ws + 2097152 + 32768);               // 32 KB

  hipLaunchKernelGGL(k_proj, dim3(512), dim3(256), 0, stream,
                     x, W, a_src, a_dst, Bp, f_src, f_dst);
  hipLaunchKernelGGL(k_attn, dim3(512), dim3(512), 0, stream,
                     adj, Bp, f_src, f_dst, out);
}

// Round 4
// 465.758 us; speedup vs baseline: 1.1590x; 1.1590x over previous
//
#include <hip/hip_runtime.h>
#include <hip/hip_bf16.h>

#define NN 8192
#define FIN 256
#define FO 128
#define KSPLIT 4
#define JCHUNK (NN / KSPLIT)    // 2048 cols per block
#define KSTEP 256               // cols per K-step
#define NSTEP (JCHUNK / KSTEP)  // 8
#define PSTRIDE 280             // bf16 k-stride of p-tile (pad: conflict-free r/w)
#define L2E 1.4426950408889634f
#define C2  0.28853900817779268f   // 0.2 * log2(e)

typedef __bf16 bf16x8 __attribute__((ext_vector_type(8)));
typedef __bf16 bf16x4 __attribute__((ext_vector_type(4)));
typedef __bf16 bf16x2 __attribute__((ext_vector_type(2)));
typedef float  f32x4  __attribute__((ext_vector_type(4)));

// ---------------------------------------------------------------------------
// Kernel 1: h = x@W (fp32 accum), write Bpack (bf16 MFMA-B-fragment layout),
//           f_src = h@a_src, f_dst = h@a_dst (fp32).
// Bpack element (kg, nt, lane=q*16+m, t) = h[j = kg*32+q*8+t][n = nt*16+m]
// ---------------------------------------------------------------------------
__global__ __launch_bounds__(256) void k_proj(
    const float* __restrict__ x, const float* __restrict__ W,
    const float* __restrict__ a_src, const float* __restrict__ a_dst,
    __bf16* __restrict__ Bp, float* __restrict__ f_src, float* __restrict__ f_dst)
{
  __shared__ float xs[16 * FIN];     // 16 KB x-tile
  __shared__ float fs[16], fd[16];
  const int tid = threadIdx.x;
  const int i0 = blockIdx.x * 16;

  const float4* xg = (const float4*)(x + (size_t)i0 * FIN);
  float4* xs4 = (float4*)xs;
  #pragma unroll
  for (int t = 0; t < 4; t++) xs4[tid + 256 * t] = xg[tid + 256 * t];
  if (tid < 16) { fs[tid] = 0.f; fd[tid] = 0.f; }
  __syncthreads();

  const int cq = tid & 31;    // column quad: cols c0..c0+3
  const int rg = tid >> 5;    // row group: rows r0, r0+1
  const int c0 = cq * 4;
  const int r0 = rg * 2;
  float acc0[4] = {0.f,0.f,0.f,0.f};
  float acc1[4] = {0.f,0.f,0.f,0.f};
  const float* xr0 = xs + r0 * FIN;
  const float* xr1 = xs + (r0 + 1) * FIN;

  for (int k = 0; k < FIN; k += 4) {
    float4 xa = *(const float4*)(xr0 + k);
    float4 xb = *(const float4*)(xr1 + k);
    #pragma unroll
    for (int kk = 0; kk < 4; kk++) {
      float4 wv = *(const float4*)(W + (size_t)(k + kk) * FO + c0);
      float xav = ((const float*)&xa)[kk];
      float xbv = ((const float*)&xb)[kk];
      acc0[0] += xav * wv.x; acc0[1] += xav * wv.y;
      acc0[2] += xav * wv.z; acc0[3] += xav * wv.w;
      acc1[0] += xbv * wv.x; acc1[1] += xbv * wv.y;
      acc1[2] += xbv * wv.z; acc1[3] += xbv * wv.w;
    }
  }

  float4 as = *(const float4*)(a_src + c0);
  float4 ad = *(const float4*)(a_dst + c0);
  float ps0 = acc0[0]*as.x + acc0[1]*as.y + acc0[2]*as.z + acc0[3]*as.w;
  float ps1 = acc1[0]*as.x + acc1[1]*as.y + acc1[2]*as.z + acc1[3]*as.w;
  float pd0 = acc0[0]*ad.x + acc0[1]*ad.y + acc0[2]*ad.z + acc0[3]*ad.w;
  float pd1 = acc1[0]*ad.x + acc1[1]*ad.y + acc1[2]*ad.z + acc1[3]*ad.w;
  atomicAdd(&fs[r0],     ps0);
  atomicAdd(&fs[r0 + 1], ps1);
  atomicAdd(&fd[r0],     pd0);
  atomicAdd(&fd[r0 + 1], pd1);

  const int j0 = i0 + r0;
  const int kg = j0 >> 5;
  const int q  = (j0 >> 3) & 3;
  const int t0 = j0 & 7;
  #pragma unroll
  for (int c = 0; c < 4; c++) {
    const int n = c0 + c;
    bf16x2 v;
    v[0] = (__bf16)acc0[c];
    v[1] = (__bf16)acc1[c];
    size_t idx = ((size_t)(kg * 8 + (n >> 4)) * 64 + q * 16 + (n & 15)) * 8 + t0;
    *(bf16x2*)(Bp + idx) = v;
  }
  __syncthreads();
  if (tid < 16) { f_src[i0 + tid] = fs[tid]; f_dst[i0 + tid] = fd[tid]; }
}

// ---------------------------------------------------------------------------
// Kernel 2 (GEMM-style): block = 32 rows x 2048-col chunk, 4 waves.
// Per 256-col step: coalesced adj row loads -> p in registers -> bf16 p-tile
// in LDS (padded stride, conflict-free) -> ds_read_b128 A-frags + global
// B-frags -> MFMA. Row-sums (softmax denom) via MFMA against all-ones B.
// ---------------------------------------------------------------------------
__global__ __launch_bounds__(256, 4) void k_attn(
    const float* __restrict__ adj, const __bf16* __restrict__ Bp,
    const float* __restrict__ f_src, const float* __restrict__ f_dst,
    float* __restrict__ num, float* __restrict__ lsum)
{
  __shared__ float fdls[JCHUNK];                             // 8 KB
  __shared__ __align__(16) __bf16 ptile[2 * 16 * PSTRIDE];   // 17.5 KB
  const int tid = threadIdx.x;
  const int rg = blockIdx.x >> 2;
  const int ks = blockIdx.x & 3;
  const int i0 = rg * 32;
  const int jbase = ks * JCHUNK;

  // stage f_dst chunk (coalesced, once)
  {
    const float4* s = (const float4*)(f_dst + jbase);
    float4* d4 = (float4*)fdls;
    d4[tid] = s[tid];
    d4[tid + 256] = s[tid + 256];
  }

  const int w = tid >> 6;
  const int lane = tid & 63;
  const int m = lane & 15;
  const int q = lane >> 4;
  const int mt = w & 1;       // which 16-row m-tile this wave computes
  const int h = w >> 1;       // which k-half (kg 0-3 vs 4-7) of each step

  float fsv[8];
  #pragma unroll
  for (int it = 0; it < 8; it++) fsv[it] = f_src[i0 + it * 4 + w];

  f32x4 acc[8];
  #pragma unroll
  for (int t = 0; t < 8; t++) acc[t] = (f32x4){0.f, 0.f, 0.f, 0.f};
  f32x4 accl = (f32x4){0.f, 0.f, 0.f, 0.f};
  bf16x8 ones;
  #pragma unroll
  for (int t = 0; t < 8; t++) ones[t] = (__bf16)1.0f;

  const float* adjb = adj + (size_t)i0 * NN + jbase + lane * 4;
  const __bf16* prd = ptile + mt * (16 * PSTRIDE) + m * PSTRIDE + q * 8;

  __syncthreads();

  // adj loads for step 0: one full coalesced row-segment per wave-instr
  float4 av[8];
  #pragma unroll
  for (int it = 0; it < 8; it++)
    av[it] = *(const float4*)(adjb + (size_t)(it * 4 + w) * NN);

  for (int step = 0; step < NSTEP; step++) {
    float4 d = *(const float4*)(fdls + step * KSTEP + lane * 4);
    float4 dl1, dl2;
    dl1.x = d.x * L2E; dl1.y = d.y * L2E; dl1.z = d.z * L2E; dl1.w = d.w * L2E;
    dl2.x = d.x * C2;  dl2.y = d.y * C2;  dl2.z = d.z * C2;  dl2.w = d.w * C2;

    if (step) __syncthreads();          // previous MFMA phase done with ptile

    #pragma unroll
    for (int it = 0; it < 8; it++) {
      const int r = it * 4 + w;
      const float s1 = fsv[it] * L2E;
      const float s2 = fsv[it] * (0.2f * L2E);
      float4 a = av[it];
      float e0 = __builtin_amdgcn_exp2f(fmaxf(dl1.x + s1, dl2.x + s2));
      float e1 = __builtin_amdgcn_exp2f(fmaxf(dl1.y + s1, dl2.y + s2));
      float e2 = __builtin_amdgcn_exp2f(fmaxf(dl1.z + s1, dl2.z + s2));
      float e3 = __builtin_amdgcn_exp2f(fmaxf(dl1.w + s1, dl2.w + s2));
      float p0 = (a.x > 0.f) ? e0 : 0.f;
      float p1 = (a.y > 0.f) ? e1 : 0.f;
      float p2 = (a.z > 0.f) ? e2 : 0.f;
      float p3 = (a.w > 0.f) ? e3 : 0.f;
      bf16x4 pv;
      pv[0] = (__bf16)p0; pv[1] = (__bf16)p1;
      pv[2] = (__bf16)p2; pv[3] = (__bf16)p3;
      *(bf16x4*)(ptile + (r >> 4) * (16 * PSTRIDE) + (r & 15) * PSTRIDE + lane * 4) = pv;
    }

    // issue next step's adj loads before the barrier (overlap with MFMA)
    if (step + 1 < NSTEP) {
      #pragma unroll
      for (int it = 0; it < 8; it++)
        av[it] = *(const float4*)(adjb + (size_t)(it * 4 + w) * NN + (step + 1) * KSTEP);
    }
    __syncthreads();

    // MFMA phase: this wave handles kg = h*4 .. h*4+3 of the step
    const int kgbase = (jbase >> 5) + step * 8;
    #pragma unroll
    for (int kk = 0; kk < 4; kk++) {
      const int kg_w = h * 4 + kk;
      bf16x8 af = *(const bf16x8*)(prd + kg_w * 32);
      const __bf16* bsrc = Bp + (size_t)(kgbase + kg_w) * 8 * 512 + lane * 8;
      #pragma unroll
      for (int nt = 0; nt < 8; nt++) {
        bf16x8 bfrag = *(const bf16x8*)(bsrc + nt * 512);
        acc[nt] = __builtin_amdgcn_mfma_f32_16x16x32_bf16(af, bfrag, acc[nt], 0, 0, 0);
      }
      accl = __builtin_amdgcn_mfma_f32_16x16x32_bf16(af, ones, accl, 0, 0, 0);
    }
  }

  // epilogue: partial sums -> global atomics (C/D: row=q*4+r, col=lane&15)
  const int rb0 = i0 + mt * 16 + q * 4;
  #pragma unroll
  for (int nt = 0; nt < 8; nt++) {
    #pragma unroll
    for (int r = 0; r < 4; r++) {
      atomicAdd(&num[(size_t)(rb0 + r) * FO + nt * 16 + m], acc[nt][r]);
    }
  }
  if (m == 0) {
    #pragma unroll
    for (int r = 0; r < 4; r++) atomicAdd(&lsum[rb0 + r], accl[r]);
  }
}

// ---------------------------------------------------------------------------
// Kernel 3: out = num / l, vectorized float4.
// ---------------------------------------------------------------------------
__global__ __launch_bounds__(256) void k_div(
    const float* __restrict__ num, const float* __restrict__ lsum,
    float* __restrict__ out)
{
  int idx = blockIdx.x * 256 + threadIdx.x;        // float4 index
  float4 v = ((const float4*)num)[idx];
  float inv = 1.0f / lsum[idx >> 5];               // 32 float4 per row
  float4 o;
  o.x = v.x * inv; o.y = v.y * inv; o.z = v.z * inv; o.w = v.w * inv;
  ((float4*)out)[idx] = o;
}

extern "C" void kernel_launch(void* const* d_in, const int* in_sizes, int n_in,
                              void* d_out, int out_size, void* d_ws, size_t ws_size,
                              hipStream_t stream) {
  const float* x     = (const float*)d_in[0];
  const float* adj   = (const float*)d_in[1];
  const float* W     = (const float*)d_in[2];
  const float* a_src = (const float*)d_in[3];
  const float* a_dst = (const float*)d_in[4];
  float* out = (float*)d_out;

  char* ws = (char*)d_ws;
  __bf16* Bp   = (__bf16*)ws;                                  // 2 MB
  float* f_src = (float*)(ws + 2097152);                       // 32 KB
  float* f_dst = (float*)(ws + 2097152 + 32768);               // 32 KB
  float* num   = (float*)(ws + 2097152 + 65536);               // 4 MB
  float* lsum  = (float*)(ws + 2097152 + 65536 + 4194304);     // 32 KB

  hipMemsetAsync(num, 0, 4194304 + 32768, stream);             // zero num + lsum
  hipLaunchKernelGGL(k_proj, dim3(512), dim3(256), 0, stream,
                     x, W, a_src, a_dst, Bp, f_src, f_dst);
  hipLaunchKernelGGL(k_attn, dim3(1024), dim3(256), 0, stream,
                     adj, Bp, f_src, f_dst, num, lsum);
  hipLaunchKernelGGL(k_div, dim3(1024), dim3(256), 0, stream,
                     num, lsum, out);
}

// Round 5
// 451.292 us; speedup vs baseline: 1.1962x; 1.0321x over previous
//
#include <hip/hip_runtime.h>
#include <hip/hip_bf16.h>

#define NN 8192
#define FIN 256
#define FO 128
#define KSPLIT 8
#define JCHUNK (NN / KSPLIT)    // 1024 cols per wave chunk
#define L2E 1.4426950408889634f
#define C2  0.28853900817779268f   // 0.2 * log2(e)

typedef __bf16 bf16x8 __attribute__((ext_vector_type(8)));
typedef __bf16 bf16x2 __attribute__((ext_vector_type(2)));
typedef float  f32x4  __attribute__((ext_vector_type(4)));

// ---------------------------------------------------------------------------
// Kernel 1: h = x@W (fp32 accum), write Bpack (bf16 MFMA-B-fragment layout),
//           f_src = h@a_src, f_dst = h@a_dst (fp32).
// Bpack element (kg, nt, lane=q*16+m, t) = h[j = kg*32+q*8+t][n = nt*16+m]
// ---------------------------------------------------------------------------
__global__ __launch_bounds__(256) void k_proj(
    const float* __restrict__ x, const float* __restrict__ W,
    const float* __restrict__ a_src, const float* __restrict__ a_dst,
    __bf16* __restrict__ Bp, float* __restrict__ f_src, float* __restrict__ f_dst)
{
  __shared__ float xs[16 * FIN];     // 16 KB x-tile
  __shared__ float fs[16], fd[16];
  const int tid = threadIdx.x;
  const int i0 = blockIdx.x * 16;

  const float4* xg = (const float4*)(x + (size_t)i0 * FIN);
  float4* xs4 = (float4*)xs;
  #pragma unroll
  for (int t = 0; t < 4; t++) xs4[tid + 256 * t] = xg[tid + 256 * t];
  if (tid < 16) { fs[tid] = 0.f; fd[tid] = 0.f; }
  __syncthreads();

  const int cq = tid & 31;    // column quad: cols c0..c0+3
  const int rg = tid >> 5;    // row group: rows r0, r0+1
  const int c0 = cq * 4;
  const int r0 = rg * 2;
  float acc0[4] = {0.f,0.f,0.f,0.f};
  float acc1[4] = {0.f,0.f,0.f,0.f};
  const float* xr0 = xs + r0 * FIN;
  const float* xr1 = xs + (r0 + 1) * FIN;

  for (int k = 0; k < FIN; k += 4) {
    float4 xa = *(const float4*)(xr0 + k);
    float4 xb = *(const float4*)(xr1 + k);
    #pragma unroll
    for (int kk = 0; kk < 4; kk++) {
      float4 wv = *(const float4*)(W + (size_t)(k + kk) * FO + c0);
      float xav = ((const float*)&xa)[kk];
      float xbv = ((const float*)&xb)[kk];
      acc0[0] += xav * wv.x; acc0[1] += xav * wv.y;
      acc0[2] += xav * wv.z; acc0[3] += xav * wv.w;
      acc1[0] += xbv * wv.x; acc1[1] += xbv * wv.y;
      acc1[2] += xbv * wv.z; acc1[3] += xbv * wv.w;
    }
  }

  float4 as = *(const float4*)(a_src + c0);
  float4 ad = *(const float4*)(a_dst + c0);
  float ps0 = acc0[0]*as.x + acc0[1]*as.y + acc0[2]*as.z + acc0[3]*as.w;
  float ps1 = acc1[0]*as.x + acc1[1]*as.y + acc1[2]*as.z + acc1[3]*as.w;
  float pd0 = acc0[0]*ad.x + acc0[1]*ad.y + acc0[2]*ad.z + acc0[3]*ad.w;
  float pd1 = acc1[0]*ad.x + acc1[1]*ad.y + acc1[2]*ad.z + acc1[3]*ad.w;
  atomicAdd(&fs[r0],     ps0);
  atomicAdd(&fs[r0 + 1], ps1);
  atomicAdd(&fd[r0],     pd0);
  atomicAdd(&fd[r0 + 1], pd1);

  const int j0 = i0 + r0;
  const int kg = j0 >> 5;
  const int q  = (j0 >> 3) & 3;
  const int t0 = j0 & 7;
  #pragma unroll
  for (int c = 0; c < 4; c++) {
    const int n = c0 + c;
    bf16x2 v;
    v[0] = (__bf16)acc0[c];
    v[1] = (__bf16)acc1[c];
    size_t idx = ((size_t)(kg * 8 + (n >> 4)) * 64 + q * 16 + (n & 15)) * 8 + t0;
    *(bf16x2*)(Bp + idx) = v;
  }
  __syncthreads();
  if (tid < 16) { f_src[i0 + tid] = fs[tid]; f_dst[i0 + tid] = fd[tid]; }
}

// ---------------------------------------------------------------------------
// Kernel 2: streaming P@H. Separable softmax weights:
//   p_ij = adj ? max(F1_i*G1_j, F2_i*G2_j) : 0   (== exp(leakyrelu(s+d)))
// 64-k steps, depth-2 register double-buffer on adj so the adj stream is
// continuously outstanding. A-frags built in registers (r2-style scatter),
// B-frags contiguous 1KB from Bpack. No barriers in loop.
// 1024 blocks x 256 threads (4 waves x 16 rows x 1024-col chunk).
// ---------------------------------------------------------------------------
__global__ __launch_bounds__(256, 4) void k_attn(
    const float* __restrict__ adj, const __bf16* __restrict__ Bp,
    const float* __restrict__ f_src, const float* __restrict__ f_dst,
    float* __restrict__ num, float* __restrict__ lsum)
{
  __shared__ float G1[JCHUNK];   // 4 KB
  __shared__ float G2[JCHUNK];   // 4 KB
  const int tid = threadIdx.x;
  const int rb = blockIdx.x >> 3;     // 0..127, 64 rows each
  const int ks = blockIdx.x & 7;
  const int jbase = ks * JCHUNK;

  #pragma unroll
  for (int t = 0; t < 4; t++) {
    int j = tid + t * 256;
    float d = f_dst[jbase + j];
    G1[j] = __builtin_amdgcn_exp2f(d * L2E);
    G2[j] = __builtin_amdgcn_exp2f(d * C2);
  }

  const int w = tid >> 6;
  const int lane = tid & 63;
  const int m = lane & 15;
  const int q = lane >> 4;
  const int i0 = rb * 64 + w * 16;
  const float s  = f_src[i0 + m];
  const float F1 = __builtin_amdgcn_exp2f(s * L2E);
  const float F2 = __builtin_amdgcn_exp2f(s * C2);

  f32x4 acc[8];
  #pragma unroll
  for (int t = 0; t < 8; t++) acc[t] = (f32x4){0.f, 0.f, 0.f, 0.f};
  float psum = 0.f;

  const float* adjp = adj + (size_t)(i0 + m) * NN + jbase + q * 8;
  const float* g1p = G1 + q * 8;
  const float* g2p = G2 + q * 8;
  const __bf16* bb = Bp + (size_t)(jbase >> 5) * 4096 + lane * 8;

  __syncthreads();

  // depth-2 double buffer: 4 x float4 (one 64-k batch) always in flight
  float4 cur0 = *(const float4*)(adjp + 0);
  float4 cur1 = *(const float4*)(adjp + 4);
  float4 cur2 = *(const float4*)(adjp + 32);
  float4 cur3 = *(const float4*)(adjp + 36);

  #pragma unroll 2
  for (int st = 0; st < 16; ++st) {
    float4 nxt0, nxt1, nxt2, nxt3;
    if (st < 15) {
      const float* ap = adjp + (st + 1) * 64;
      nxt0 = *(const float4*)(ap + 0);
      nxt1 = *(const float4*)(ap + 4);
      nxt2 = *(const float4*)(ap + 32);
      nxt3 = *(const float4*)(ap + 36);
    }
    #pragma unroll
    for (int g = 0; g < 2; ++g) {
      const int ko = st * 64 + g * 32;
      float4 a0 = g ? cur2 : cur0;
      float4 a1 = g ? cur3 : cur1;
      float4 u0 = *(const float4*)(g1p + ko);
      float4 u1 = *(const float4*)(g1p + ko + 4);
      float4 v0 = *(const float4*)(g2p + ko);
      float4 v1 = *(const float4*)(g2p + ko + 4);
      float p0 = (a0.x > 0.f) ? fmaxf(F1 * u0.x, F2 * v0.x) : 0.f;
      float p1 = (a0.y > 0.f) ? fmaxf(F1 * u0.y, F2 * v0.y) : 0.f;
      float p2 = (a0.z > 0.f) ? fmaxf(F1 * u0.z, F2 * v0.z) : 0.f;
      float p3 = (a0.w > 0.f) ? fmaxf(F1 * u0.w, F2 * v0.w) : 0.f;
      float p4 = (a1.x > 0.f) ? fmaxf(F1 * u1.x, F2 * v1.x) : 0.f;
      float p5 = (a1.y > 0.f) ? fmaxf(F1 * u1.y, F2 * v1.y) : 0.f;
      float p6 = (a1.z > 0.f) ? fmaxf(F1 * u1.z, F2 * v1.z) : 0.f;
      float p7 = (a1.w > 0.f) ? fmaxf(F1 * u1.w, F2 * v1.w) : 0.f;
      psum += ((p0 + p1) + (p2 + p3)) + ((p4 + p5) + (p6 + p7));

      bf16x8 af;
      af[0] = (__bf16)p0; af[1] = (__bf16)p1; af[2] = (__bf16)p2; af[3] = (__bf16)p3;
      af[4] = (__bf16)p4; af[5] = (__bf16)p5; af[6] = (__bf16)p6; af[7] = (__bf16)p7;

      const __bf16* bs = bb + (size_t)(st * 2 + g) * 4096;
      #pragma unroll
      for (int nt = 0; nt < 8; nt++) {
        bf16x8 bfrag = *(const bf16x8*)(bs + nt * 512);
        acc[nt] = __builtin_amdgcn_mfma_f32_16x16x32_bf16(af, bfrag, acc[nt], 0, 0, 0);
      }
    }
    if (st < 15) { cur0 = nxt0; cur1 = nxt1; cur2 = nxt2; cur3 = nxt3; }
  }

  // denominator: rows keyed by m live in lanes {m, m+16, m+32, m+48}
  psum += __shfl_xor(psum, 16);
  psum += __shfl_xor(psum, 32);
  if (lane < 16) atomicAdd(&lsum[i0 + lane], psum);

  // numerator: C/D layout row=(lane>>4)*4+r, col=lane&15
  #pragma unroll
  for (int nt = 0; nt < 8; nt++) {
    #pragma unroll
    for (int r = 0; r < 4; r++) {
      atomicAdd(&num[(size_t)(i0 + q * 4 + r) * FO + nt * 16 + m], acc[nt][r]);
    }
  }
}

// ---------------------------------------------------------------------------
// Kernel 3: out = num / l, vectorized float4.
// ---------------------------------------------------------------------------
__global__ __launch_bounds__(256) void k_div(
    const float* __restrict__ num, const float* __restrict__ lsum,
    float* __restrict__ out)
{
  int idx = blockIdx.x * 256 + threadIdx.x;        // float4 index
  float4 v = ((const float4*)num)[idx];
  float inv = 1.0f / lsum[idx >> 5];               // 32 float4 per row
  float4 o;
  o.x = v.x * inv; o.y = v.y * inv; o.z = v.z * inv; o.w = v.w * inv;
  ((float4*)out)[idx] = o;
}

extern "C" void kernel_launch(void* const* d_in, const int* in_sizes, int n_in,
                              void* d_out, int out_size, void* d_ws, size_t ws_size,
                              hipStream_t stream) {
  const float* x     = (const float*)d_in[0];
  const float* adj   = (const float*)d_in[1];
  const float* W     = (const float*)d_in[2];
  const float* a_src = (const float*)d_in[3];
  const float* a_dst = (const float*)d_in[4];
  float* out = (float*)d_out;

  char* ws = (char*)d_ws;
  __bf16* Bp   = (__bf16*)ws;                                  // 2 MB
  float* f_src = (float*)(ws + 2097152);                       // 32 KB
  float* f_dst = (float*)(ws + 2097152 + 32768);               // 32 KB
  float* num   = (float*)(ws + 2097152 + 65536);               // 4 MB
  float* lsum  = (float*)(ws + 2097152 + 65536 + 4194304);     // 32 KB

  hipMemsetAsync(num, 0, 4194304 + 32768, stream);             // zero num + lsum
  hipLaunchKernelGGL(k_proj, dim3(512), dim3(256), 0, stream,
                     x, W, a_src, a_dst, Bp, f_src, f_dst);
  hipLaunchKernelGGL(k_attn, dim3(1024), dim3(256), 0, stream,
                     adj, Bp, f_src, f_dst, num, lsum);
  hipLaunchKernelGGL(k_div, dim3(1024), dim3(256), 0, stream,
                     num, lsum, out);
}

// Round 6
// 448.363 us; speedup vs baseline: 1.2040x; 1.0065x over previous
//
#include <hip/hip_runtime.h>
#include <hip/hip_bf16.h>

#define NN 8192
#define FIN 256
#define FO 128
#define KSPLIT 8
#define JCHUNK 1024             // cols per wave
#define NSTEP 16                // 64-col steps
#define GSTRIDE 260             // floats per 4-row LDS group (1024 B + 16 B pad)
#define L2E 1.4426950408889634f
#define C2  0.28853900817779268f   // 0.2 * log2(e)

typedef __bf16 bf16x8 __attribute__((ext_vector_type(8)));
typedef __bf16 bf16x2 __attribute__((ext_vector_type(2)));
typedef float  f32x4  __attribute__((ext_vector_type(4)));

__device__ __forceinline__ void dma16(const float* g, float* l) {
  __builtin_amdgcn_global_load_lds(
      (__attribute__((address_space(1))) void*)g,
      (__attribute__((address_space(3))) void*)l, 16, 0, 0);
}

// ---------------------------------------------------------------------------
// Kernel 1: h = x@W (fp32 accum), write Bpack (bf16 MFMA-B-fragment layout),
//           f_src = h@a_src, f_dst = h@a_dst (fp32).
// Bpack element (kg, nt, lane=q*16+m, t) = h[j = kg*32+q*8+t][n = nt*16+m]
// ---------------------------------------------------------------------------
__global__ __launch_bounds__(256) void k_proj(
    const float* __restrict__ x, const float* __restrict__ W,
    const float* __restrict__ a_src, const float* __restrict__ a_dst,
    __bf16* __restrict__ Bp, float* __restrict__ f_src, float* __restrict__ f_dst)
{
  __shared__ float xs[16 * FIN];     // 16 KB x-tile
  __shared__ float fs[16], fd[16];
  const int tid = threadIdx.x;
  const int i0 = blockIdx.x * 16;

  const float4* xg = (const float4*)(x + (size_t)i0 * FIN);
  float4* xs4 = (float4*)xs;
  #pragma unroll
  for (int t = 0; t < 4; t++) xs4[tid + 256 * t] = xg[tid + 256 * t];
  if (tid < 16) { fs[tid] = 0.f; fd[tid] = 0.f; }
  __syncthreads();

  const int cq = tid & 31;    // column quad: cols c0..c0+3
  const int rg = tid >> 5;    // row group: rows r0, r0+1
  const int c0 = cq * 4;
  const int r0 = rg * 2;
  float acc0[4] = {0.f,0.f,0.f,0.f};
  float acc1[4] = {0.f,0.f,0.f,0.f};
  const float* xr0 = xs + r0 * FIN;
  const float* xr1 = xs + (r0 + 1) * FIN;

  for (int k = 0; k < FIN; k += 4) {
    float4 xa = *(const float4*)(xr0 + k);
    float4 xb = *(const float4*)(xr1 + k);
    #pragma unroll
    for (int kk = 0; kk < 4; kk++) {
      float4 wv = *(const float4*)(W + (size_t)(k + kk) * FO + c0);
      float xav = ((const float*)&xa)[kk];
      float xbv = ((const float*)&xb)[kk];
      acc0[0] += xav * wv.x; acc0[1] += xav * wv.y;
      acc0[2] += xav * wv.z; acc0[3] += xav * wv.w;
      acc1[0] += xbv * wv.x; acc1[1] += xbv * wv.y;
      acc1[2] += xbv * wv.z; acc1[3] += xbv * wv.w;
    }
  }

  float4 as = *(const float4*)(a_src + c0);
  float4 ad = *(const float4*)(a_dst + c0);
  float ps0 = acc0[0]*as.x + acc0[1]*as.y + acc0[2]*as.z + acc0[3]*as.w;
  float ps1 = acc1[0]*as.x + acc1[1]*as.y + acc1[2]*as.z + acc1[3]*as.w;
  float pd0 = acc0[0]*ad.x + acc0[1]*ad.y + acc0[2]*ad.z + acc0[3]*ad.w;
  float pd1 = acc1[0]*ad.x + acc1[1]*ad.y + acc1[2]*ad.z + acc1[3]*ad.w;
  atomicAdd(&fs[r0],     ps0);
  atomicAdd(&fs[r0 + 1], ps1);
  atomicAdd(&fd[r0],     pd0);
  atomicAdd(&fd[r0 + 1], pd1);

  const int j0 = i0 + r0;
  const int kg = j0 >> 5;
  const int q  = (j0 >> 3) & 3;
  const int t0 = j0 & 7;
  #pragma unroll
  for (int c = 0; c < 4; c++) {
    const int n = c0 + c;
    bf16x2 v;
    v[0] = (__bf16)acc0[c];
    v[1] = (__bf16)acc1[c];
    size_t idx = ((size_t)(kg * 8 + (n >> 4)) * 64 + q * 16 + (n & 15)) * 8 + t0;
    *(bf16x2*)(Bp + idx) = v;
  }
  __syncthreads();
  if (tid < 16) { f_src[i0 + tid] = fs[tid]; f_dst[i0 + tid] = fd[tid]; }
}

// ---------------------------------------------------------------------------
// Kernel 2: DMA-staged streaming P@H.
// 512 blocks x 256 thr (4 waves). Wave owns 32 rows x 1024 cols; two 16-row
// m-tiles share each B-frag (halves Bp traffic). Per 64-col step: 8 async
// global_load_lds DMAs (4 rows each, 16B/lane, 8KB in flight) into per-wave
// double-buffered LDS; issue(next) -> __syncthreads (vmcnt drain) -> consume.
// Separable softmax: p = adj ? max(F1_i*G1_j, F2_i*G2_j) : 0.
// LDS tile padded 16B per 4-row group: A-frag read is 4-way conflict only.
// ---------------------------------------------------------------------------
__global__ __launch_bounds__(256, 2) void k_attn(
    const float* __restrict__ adj, const __bf16* __restrict__ Bp,
    const float* __restrict__ f_src, const float* __restrict__ f_dst,
    float* __restrict__ num, float* __restrict__ lsum)
{
  __shared__ float G1[JCHUNK];                         // 4 KB
  __shared__ float G2[JCHUNK];                         // 4 KB
  __shared__ __align__(16) float atile[4][2][8 * GSTRIDE];  // 65 KB

  const int tid = threadIdx.x;
  const int rb = blockIdx.x >> 3;     // 0..63 (128 rows per block)
  const int ks = blockIdx.x & 7;
  const int i0 = rb * 128;
  const int jbase = ks * JCHUNK;

  #pragma unroll
  for (int t = 0; t < 4; t++) {
    int j = tid + t * 256;
    float d = f_dst[jbase + j];
    G1[j] = __builtin_amdgcn_exp2f(d * L2E);
    G2[j] = __builtin_amdgcn_exp2f(d * C2);
  }

  const int w = tid >> 6;
  const int lane = tid & 63;
  const int m = lane & 15;
  const int q = lane >> 4;
  const int wbase = i0 + w * 32;

  float F1[2], F2[2];
  #pragma unroll
  for (int mt = 0; mt < 2; mt++) {
    float s = f_src[wbase + mt * 16 + m];
    F1[mt] = __builtin_amdgcn_exp2f(s * L2E);
    F2[mt] = __builtin_amdgcn_exp2f(s * C2);
  }

  f32x4 acc[2][8];
  #pragma unroll
  for (int mt = 0; mt < 2; mt++)
    #pragma unroll
    for (int nt = 0; nt < 8; nt++) acc[mt][nt] = (f32x4){0.f, 0.f, 0.f, 0.f};
  float psum[2] = {0.f, 0.f};

  // DMA source: lane covers row (lane>>4) of each 4-row group, 16B at (lane&15)*16
  const float* gsrc = adj + (size_t)(wbase + (lane >> 4)) * NN + jbase + (lane & 15) * 4;
  float* tw0 = &atile[w][0][0];
  float* tw1 = &atile[w][1][0];

#define ISSUE(buf, step)                                                      \
  {                                                                           \
    const float* gs = gsrc + (step) * 64;                                     \
    float* lb = (buf) ? tw1 : tw0;                                            \
    _Pragma("unroll")                                                         \
    for (int g = 0; g < 8; g++)                                               \
      dma16(gs + (size_t)g * 4 * NN, lb + g * GSTRIDE);                       \
  }

  ISSUE(0, 0)

  for (int step = 0; step < NSTEP; ++step) {
    const int buf = step & 1;
    if (step + 1 < NSTEP) ISSUE(buf ^ 1, step + 1)
    __syncthreads();                 // drains DMA queue (vmcnt 0) + barrier

    const float* tb = buf ? tw1 : tw0;
    #pragma unroll
    for (int kg = 0; kg < 2; kg++) {
      const int jj = step * 64 + kg * 32 + q * 8;
      float4 u0 = *(const float4*)(G1 + jj);
      float4 u1 = *(const float4*)(G1 + jj + 4);
      float4 v0 = *(const float4*)(G2 + jj);
      float4 v1 = *(const float4*)(G2 + jj + 4);

      bf16x8 af[2];
      #pragma unroll
      for (int mt = 0; mt < 2; mt++) {
        const int r = mt * 16 + m;
        const float* ap = tb + (r >> 2) * GSTRIDE + (r & 3) * 64 + kg * 32 + q * 8;
        float4 a0 = *(const float4*)ap;
        float4 a1 = *(const float4*)(ap + 4);
        const float f1 = F1[mt], f2 = F2[mt];
        float p0 = (a0.x > 0.f) ? fmaxf(f1 * u0.x, f2 * v0.x) : 0.f;
        float p1 = (a0.y > 0.f) ? fmaxf(f1 * u0.y, f2 * v0.y) : 0.f;
        float p2 = (a0.z > 0.f) ? fmaxf(f1 * u0.z, f2 * v0.z) : 0.f;
        float p3 = (a0.w > 0.f) ? fmaxf(f1 * u0.w, f2 * v0.w) : 0.f;
        float p4 = (a1.x > 0.f) ? fmaxf(f1 * u1.x, f2 * v1.x) : 0.f;
        float p5 = (a1.y > 0.f) ? fmaxf(f1 * u1.y, f2 * v1.y) : 0.f;
        float p6 = (a1.z > 0.f) ? fmaxf(f1 * u1.z, f2 * v1.z) : 0.f;
        float p7 = (a1.w > 0.f) ? fmaxf(f1 * u1.w, f2 * v1.w) : 0.f;
        psum[mt] += ((p0 + p1) + (p2 + p3)) + ((p4 + p5) + (p6 + p7));
        bf16x8 a;
        a[0] = (__bf16)p0; a[1] = (__bf16)p1; a[2] = (__bf16)p2; a[3] = (__bf16)p3;
        a[4] = (__bf16)p4; a[5] = (__bf16)p5; a[6] = (__bf16)p6; a[7] = (__bf16)p7;
        af[mt] = a;
      }

      const __bf16* bsrc = Bp + (size_t)(ks * 32 + step * 2 + kg) * 4096 + lane * 8;
      #pragma unroll
      for (int nt = 0; nt < 8; nt++) {
        bf16x8 bfrag = *(const bf16x8*)(bsrc + nt * 512);
        acc[0][nt] = __builtin_amdgcn_mfma_f32_16x16x32_bf16(af[0], bfrag, acc[0][nt], 0, 0, 0);
        acc[1][nt] = __builtin_amdgcn_mfma_f32_16x16x32_bf16(af[1], bfrag, acc[1][nt], 0, 0, 0);
      }
    }
  }
#undef ISSUE

  // denominators: rows keyed by m live in lanes {m, m+16, m+32, m+48}
  #pragma unroll
  for (int mt = 0; mt < 2; mt++) {
    float p = psum[mt];
    p += __shfl_xor(p, 16);
    p += __shfl_xor(p, 32);
    if (lane < 16) atomicAdd(&lsum[wbase + mt * 16 + lane], p);
  }

  // numerators: C/D layout row=q*4+r, col=nt*16+m
  #pragma unroll
  for (int mt = 0; mt < 2; mt++) {
    const int rb0 = wbase + mt * 16 + q * 4;
    #pragma unroll
    for (int nt = 0; nt < 8; nt++) {
      #pragma unroll
      for (int r = 0; r < 4; r++) {
        atomicAdd(&num[(size_t)(rb0 + r) * FO + nt * 16 + m], acc[mt][nt][r]);
      }
    }
  }
}

// ---------------------------------------------------------------------------
// Kernel 3: out = num / l, vectorized float4.
// ---------------------------------------------------------------------------
__global__ __launch_bounds__(256) void k_div(
    const float* __restrict__ num, const float* __restrict__ lsum,
    float* __restrict__ out)
{
  int idx = blockIdx.x * 256 + threadIdx.x;        // float4 index
  float4 v = ((const float4*)num)[idx];
  float inv = 1.0f / lsum[idx >> 5];               // 32 float4 per row
  float4 o;
  o.x = v.x * inv; o.y = v.y * inv; o.z = v.z * inv; o.w = v.w * inv;
  ((float4*)out)[idx] = o;
}

extern "C" void kernel_launch(void* const* d_in, const int* in_sizes, int n_in,
                              void* d_out, int out_size, void* d_ws, size_t ws_size,
                              hipStream_t stream) {
  const float* x     = (const float*)d_in[0];
  const float* adj   = (const float*)d_in[1];
  const float* W     = (const float*)d_in[2];
  const float* a_src = (const float*)d_in[3];
  const float* a_dst = (const float*)d_in[4];
  float* out = (float*)d_out;

  char* ws = (char*)d_ws;
  __bf16* Bp   = (__bf16*)ws;                                  // 2 MB
  float* f_src = (float*)(ws + 2097152);                       // 32 KB
  float* f_dst = (float*)(ws + 2097152 + 32768);               // 32 KB
  float* num   = (float*)(ws + 2097152 + 65536);               // 4 MB
  float* lsum  = (float*)(ws + 2097152 + 65536 + 4194304);     // 32 KB

  hipMemsetAsync(num, 0, 4194304 + 32768, stream);             // zero num + lsum
  hipLaunchKernelGGL(k_proj, dim3(512), dim3(256), 0, stream,
                     x, W, a_src, a_dst, Bp, f_src, f_dst);
  hipLaunchKernelGGL(k_attn, dim3(512), dim3(256), 0, stream,
                     adj, Bp, f_src, f_dst, num, lsum);
  hipLaunchKernelGGL(k_div, dim3(1024), dim3(256), 0, stream,
                     num, lsum, out);
}